// Round 6
// baseline (12673.558 us; speedup 1.0000x reference)
//
#include <hip/hip_runtime.h>
#include <hip/hip_bf16.h>

#define B    256
#define S    192
#define F    64
#define HD   1024
#define PRED 48
#define TSTART (S - 1 - PRED)   // 143
#define NBLK 64

typedef __attribute__((ext_vector_type(8))) short short8;
typedef __attribute__((ext_vector_type(4))) float f32x4;
typedef unsigned long long u64;
typedef unsigned int u32;

static __device__ __forceinline__ short f2bf(float f) {
    __hip_bfloat16 h = __float2bfloat16(f);
    return *reinterpret_cast<short*>(&h);
}

// Relaxed agent-scope ("sc1", MALL-serviced) state access — round-4-proven:
// no cache-maintenance instructions emitted, weights stay L2-resident.
static __device__ __forceinline__ void st_state(short* p, short v) {
    __hip_atomic_store(p, v, __ATOMIC_RELAXED, __HIP_MEMORY_SCOPE_AGENT);
}

static __device__ __forceinline__ f32x4 mfma16(short8 a, short8 b, f32x4 c) {
    return __builtin_amdgcn_mfma_f32_16x16x32_bf16(a, b, c, 0, 0, 0);
}

// ---------------------------------------------------------------------------
// prep kernels (unchanged, proven rounds 1-4)
// ---------------------------------------------------------------------------
__global__ void fold_kernel(const float* __restrict__ Wh,
                            const float* __restrict__ Wih0,
                            float* __restrict__ Wfold) {
    const int n  = (blockIdx.x & 3) * 256 + threadIdx.x;
    const int f0 = (blockIdx.x >> 2) * 4;
    float a0 = 0.f, a1 = 0.f, a2 = 0.f, a3 = 0.f;
#pragma unroll 8
    for (int k = 0; k < HD; ++k) {
        const float w = Wih0[(size_t)k * HD + n];
        a0 += Wh[(f0 + 0) * HD + k] * w;
        a1 += Wh[(f0 + 1) * HD + k] * w;
        a2 += Wh[(f0 + 2) * HD + k] * w;
        a3 += Wh[(f0 + 3) * HD + k] * w;
    }
    Wfold[(f0 + 0) * HD + n] = a0;
    Wfold[(f0 + 1) * HD + n] = a1;
    Wfold[(f0 + 2) * HD + n] = a2;
    Wfold[(f0 + 3) * HD + n] = a3;
}

__global__ void bias_kernel(const float* __restrict__ bh,
                            const float* __restrict__ Wih0,
                            const float* __restrict__ bih,
                            const float* __restrict__ bhh,
                            float* __restrict__ bf0,
                            float* __restrict__ bf1) {
    const int n = blockIdx.x * 256 + threadIdx.x;
    float a = 0.f;
#pragma unroll 8
    for (int k = 0; k < HD; ++k) a += bh[k] * Wih0[(size_t)k * HD + n];
    bf0[n] = a + bih[n] + bhh[n];
    bf1[n] = bih[HD + n] + bhh[HD + n];
}

__global__ void transpose_cast(const float* __restrict__ src,
                               short* __restrict__ dst, int K, int N) {
    __shared__ float tile[64][65];
    const int nk = K >> 6;
    const int bk = blockIdx.x % nk;
    const int bn = blockIdx.x / nk;
    const int i  = threadIdx.x;
    {
        const int c4 = (i & 15) * 4;
        for (int it = 0; it < 4; ++it) {
            const int k = (i >> 4) + it * 16;
            const float4 v = *reinterpret_cast<const float4*>(
                &src[(size_t)(bk * 64 + k) * N + bn * 64 + c4]);
            tile[k][c4 + 0] = v.x; tile[k][c4 + 1] = v.y;
            tile[k][c4 + 2] = v.z; tile[k][c4 + 3] = v.w;
        }
    }
    __syncthreads();
    {
        const int n  = i >> 2;
        const int kb = (i & 3) * 16;
        short* dp = &dst[(size_t)(bn * 64 + n) * K + bk * 64 + kb];
#pragma unroll
        for (int j = 0; j < 16; ++j) dp[j] = f2bf(tile[kb + j][n]);
    }
}

__global__ void xcast(const float* __restrict__ x, short* __restrict__ xb) {
    const size_t i = ((size_t)blockIdx.x * 256 + threadIdx.x) * 4;
    const float4 v = *reinterpret_cast<const float4*>(&x[i]);
    short4 o;
    o.x = f2bf(v.x); o.y = f2bf(v.y); o.z = f2bf(v.z); o.w = f2bf(v.w);
    *reinterpret_cast<short4*>(&xb[i]) = o;
}

// ---------------------------------------------------------------------------
// stage32: copy 32 rows x 1024 cols of bf16 state (rows row0..row0+31) into
// LDS, XOR-swizzled (byte ^= (row&7)<<4) so stride-2048 ds_read_b128 is
// conflict-light. Loads are relaxed agent-scope (coherent via MALL).
// 512 threads x 16 iters x 8B = 64 KB.
// ---------------------------------------------------------------------------
static __device__ __forceinline__ void stage32(short* lds, const short* src,
                                               int row0) {
    const int tid = threadIdx.x;
#pragma unroll
    for (int it = 0; it < 16; ++it) {
        const int c  = it * 512 + tid;
        const int r  = c >> 8;              // 0..31
        const int kb = (c & 255) << 3;      // byte offset within row
        const u64 v = __hip_atomic_load(
            (const u64*)((const char*)(src + (size_t)(row0 + r) * HD) + kb),
            __ATOMIC_RELAXED, __HIP_MEMORY_SCOPE_AGENT);
        *(u64*)((char*)lds + r * 2048 + (kb ^ ((r & 7) << 4))) = v;
    }
}

// ---------------------------------------------------------------------------
// gemm_lds4: acc[c] += A_lds(16x1024, swizzled) @ B_cols(c*16), K=1024.
// A from LDS (shared by all waves), B from global (L2-hot weight slice).
// bp already includes (n0+lr)*HD + kg*8.
// ---------------------------------------------------------------------------
static __device__ __forceinline__ void gemm_lds4(
    const short* lds, int abase, int aswz, const short* __restrict__ bp,
    f32x4 acc[4]) {
    const char* lb = (const char*)lds;
#pragma unroll 4
    for (int k0 = 0; k0 < HD; k0 += 32) {
        const short8 a = *(const short8*)(lb + abase + (((k0 << 1) & 0x7FF0 | (abase & 0)) , ((k0 << 1)) ^ 0));
        (void)a;
        break;
    }
    // (rewritten below without the accidental expression)
#pragma unroll 4
    for (int k0 = 0; k0 < HD; k0 += 32) {
        const int kb = (k0 << 1);           // + kg*16 folded into abase
        const short8 a2 = *(const short8*)(lb + ((abase + kb) ^ aswz));
#pragma unroll
        for (int c = 0; c < 4; ++c) {
            const short8 b = *(const short8*)(bp + (size_t)c * 16 * HD + k0);
            acc[c] = mfma16(a2, b, acc[c]);
        }
    }
}

// Round-4-proven global barrier: monotonic counter + epoch, relaxed agent
// atomics; __syncthreads drains vmcnt(0) (sc1 stores visible) before arrival.
static __device__ __forceinline__ void gridbar(u32* ctr, u32* epoch, u32 target) {
    __syncthreads();
    if (threadIdx.x == 0) {
        const u32 a = __hip_atomic_fetch_add(ctr, 1u, __ATOMIC_RELAXED,
                                             __HIP_MEMORY_SCOPE_AGENT);
        if (a == target * NBLK - 1u) {
            __hip_atomic_store(epoch, target, __ATOMIC_RELAXED,
                               __HIP_MEMORY_SCOPE_AGENT);
        } else {
            while (__hip_atomic_load(epoch, __ATOMIC_RELAXED,
                                     __HIP_MEMORY_SCOPE_AGENT) < target)
                __builtin_amdgcn_s_sleep(2);
        }
    }
    __syncthreads();
}

// ---------------------------------------------------------------------------
// Persistent skewed recurrence, 64 blocks x 512 thr (8 waves).
// Block = one 32row x 256col tile of one layer (role = bid>>5).
// Phase k: role0 -> h0(k) (k<191); role1 -> h1(k-1) (k>=1).
// A-state staged once per block per GEMM into 64KB LDS (sc1 loads);
// weights stream from L2 (same slice every phase). One global barrier/phase.
// ---------------------------------------------------------------------------
__global__ __launch_bounds__(512, 1) void rnn_p(
    const short* __restrict__ xbf,
    const short* __restrict__ WfoldT, const float* __restrict__ bf0,
    const short* __restrict__ WhhT0, const short* __restrict__ WihT1,
    const short* __restrict__ WhhT1, const float* __restrict__ bf1,
    short* h0p0, short* h0p1, short* h1p0, short* h1p1,
    short* Hbuf, u32* ctr, u32* epoch) {

    extern __shared__ short lds[];          // 64 KB

    const int bid  = blockIdx.x;
    const int role = bid >> 5;              // 0: layer0, 1: layer1
    const int lb   = bid & 31;
    const int rt   = lb >> 2;               // 0..7  (32-row group)
    const int ct   = lb & 3;                // 0..3  (256-col group)
    const int w    = threadIdx.x >> 6;      // 0..7
    const int mh   = w & 1;                 // 16-row half
    const int nq   = w >> 1;                // 0..3 (64-col quarter)
    const int l    = threadIdx.x & 63;
    const int lr   = l & 15, kg = l >> 4;
    const int row0 = rt * 32;
    const int m0   = row0 + mh * 16;
    const int n0   = ct * 256 + nq * 64;
    const int rb   = m0 + kg * 4;
    const int arow_l = mh * 16 + lr;
    const int abase  = arow_l * 2048 + kg * 16;  // lane LDS byte base
    const int aswz   = (arow_l & 7) << 4;

    float bb[4];
    const float* bf = role ? bf1 : bf0;
#pragma unroll
    for (int c = 0; c < 4; ++c) bb[c] = bf[n0 + c * 16 + lr];

    for (int k = 0; k < S; ++k) {
        const short* h0prev = (k & 1) ? h0p0 : h0p1;   // h0(k-1)
        short*       h0cur  = (k & 1) ? h0p1 : h0p0;   // h0(k)
        const short* h1prev = (k & 1) ? h1p1 : h1p0;   // h1(k-2)
        short*       h1cur  = (k & 1) ? h1p0 : h1p1;   // h1(k-1)

        if (role == 0) {
            if (k < S - 1) {
                f32x4 acc[4] = {{0.f,0.f,0.f,0.f},{0.f,0.f,0.f,0.f},
                                {0.f,0.f,0.f,0.f},{0.f,0.f,0.f,0.f}};
                // x(k) @ Wfold  (K=64, cached reads)
                const short* xp = xbf + ((size_t)(m0 + lr) * S + k) * F + kg * 8;
                const short8 xa0 = *(const short8*)xp;
                const short8 xa1 = *(const short8*)(xp + 32);
#pragma unroll
                for (int c = 0; c < 4; ++c) {
                    const short* wf = WfoldT + (size_t)(n0 + c * 16 + lr) * F + kg * 8;
                    acc[c] = mfma16(xa0, *(const short8*)wf, acc[c]);
                    acc[c] = mfma16(xa1, *(const short8*)(wf + 32), acc[c]);
                }
                if (k > 0) {
                    stage32(lds, h0prev, row0);        // LDS free: gridbar synced
                    __syncthreads();
                    gemm_lds4(lds, abase, aswz,
                              WhhT0 + (size_t)(n0 + lr) * HD + kg * 8, acc);
                }
#pragma unroll
                for (int c = 0; c < 4; ++c)
#pragma unroll
                    for (int r = 0; r < 4; ++r)
                        st_state(&h0cur[(size_t)(rb + r) * HD + n0 + c * 16 + lr],
                                 f2bf(tanhf(acc[c][r] + bb[c])));
            }
        } else {
            if (k >= 1) {
                const int t = k - 1;
                f32x4 acc[4] = {{0.f,0.f,0.f,0.f},{0.f,0.f,0.f,0.f},
                                {0.f,0.f,0.f,0.f},{0.f,0.f,0.f,0.f}};
                stage32(lds, h0prev, row0);            // h0(k-1)
                __syncthreads();
                gemm_lds4(lds, abase, aswz,
                          WihT1 + (size_t)(n0 + lr) * HD + kg * 8, acc);
                if (t > 0) {
                    __syncthreads();                   // gemm1 reads done
                    stage32(lds, h1prev, row0);        // h1(t-1)
                    __syncthreads();
                    gemm_lds4(lds, abase, aswz,
                              WhhT1 + (size_t)(n0 + lr) * HD + kg * 8, acc);
                }
#pragma unroll
                for (int c = 0; c < 4; ++c) {
#pragma unroll
                    for (int r = 0; r < 4; ++r) {
                        const float v = tanhf(acc[c][r] + bb[c]);
                        st_state(&h1cur[(size_t)(rb + r) * HD + n0 + c * 16 + lr],
                                 f2bf(v));
                        if (t >= TSTART) {
                            const float rv = v > 0.f ? v : 0.f;
                            Hbuf[((size_t)(rb + r) * PRED + (t - TSTART)) * HD
                                 + n0 + c * 16 + lr] = f2bf(rv);
                        }
                    }
                }
            }
        }
        if (k < S - 1) gridbar(ctr, epoch, (u32)(k + 1));
    }
}

// ---------------------------------------------------------------------------
// outgemm: out = relu(H) @ WoT + bo ; M=12288, N=64, K=1024. (proven)
// ---------------------------------------------------------------------------
__global__ __launch_bounds__(256) void outgemm(
    const short* __restrict__ Hbuf, const short* __restrict__ WoT,
    const float* __restrict__ bo, float* __restrict__ out) {
    const int w = threadIdx.x >> 6, l = threadIdx.x & 63;
    const int lr = l & 15, kg = l >> 4;
    const int m0 = blockIdx.x * 64 + w * 16;
    const int arow = m0 + lr;

    f32x4 acc[4] = {{0.f,0.f,0.f,0.f},{0.f,0.f,0.f,0.f},
                    {0.f,0.f,0.f,0.f},{0.f,0.f,0.f,0.f}};
    const short* ap = Hbuf + (size_t)arow * HD + kg * 8;
    const short* bp = WoT + (size_t)lr * HD + kg * 8;
#pragma unroll 4
    for (int k0 = 0; k0 < HD; k0 += 32) {
        const short8 a = *reinterpret_cast<const short8*>(ap + k0);
#pragma unroll
        for (int c = 0; c < 4; ++c) {
            const short8 b = *reinterpret_cast<const short8*>(bp + (size_t)c * 16 * HD + k0);
            acc[c] = mfma16(a, b, acc[c]);
        }
    }
    const int rb = m0 + kg * 4;
#pragma unroll
    for (int c = 0; c < 4; ++c) {
        const float bbv = bo[c * 16 + lr];
#pragma unroll
        for (int r = 0; r < 4; ++r)
            out[(size_t)(rb + r) * F + c * 16 + lr] = acc[c][r] + bbv;
    }
}

// ---------------------------------------------------------------------------
extern "C" void kernel_launch(void* const* d_in, const int* in_sizes, int n_in,
                              void* d_out, int out_size, void* d_ws, size_t ws_size,
                              hipStream_t stream) {
    const float* x   = (const float*)d_in[0];
    const float* Wh  = (const float*)d_in[1];
    const float* bh  = (const float*)d_in[2];
    const float* Wih = (const float*)d_in[3];
    const float* Whh = (const float*)d_in[4];
    const float* bih = (const float*)d_in[5];
    const float* bhh = (const float*)d_in[6];
    const float* Wo  = (const float*)d_in[7];
    const float* bo  = (const float*)d_in[8];
    float* out = (float*)d_out;

    char* p = (char*)d_ws;
    float* Wfold  = (float*)p; p += (size_t)F * HD * 4;
    float* bf0    = (float*)p; p += HD * 4;
    float* bf1    = (float*)p; p += HD * 4;
    short* WfoldT = (short*)p; p += (size_t)HD * F * 2;
    short* WhhT0  = (short*)p; p += (size_t)HD * HD * 2;
    short* WihT1  = (short*)p; p += (size_t)HD * HD * 2;
    short* WhhT1  = (short*)p; p += (size_t)HD * HD * 2;
    short* WoT    = (short*)p; p += (size_t)F * HD * 2;
    short* h0p0   = (short*)p; p += (size_t)B * HD * 2;
    short* h0p1   = (short*)p; p += (size_t)B * HD * 2;
    short* h1p0   = (short*)p; p += (size_t)B * HD * 2;
    short* h1p1   = (short*)p; p += (size_t)B * HD * 2;
    short* Hbuf   = (short*)p; p += (size_t)B * PRED * HD * 2;
    short* xbf    = (short*)p; p += (size_t)B * S * F * 2;
    u32*   sync   = (u32*)p;  p += 4096;

    hipMemsetAsync(sync, 0, 4096, stream);

    fold_kernel<<<64, 256, 0, stream>>>(Wh, Wih, Wfold);
    bias_kernel<<<4, 256, 0, stream>>>(bh, Wih, bih, bhh, bf0, bf1);
    transpose_cast<<<16, 256, 0, stream>>>(Wfold, WfoldT, F, HD);
    transpose_cast<<<256, 256, 0, stream>>>(Whh, WhhT0, HD, HD);
    transpose_cast<<<256, 256, 0, stream>>>(Wih + (size_t)HD * HD, WihT1, HD, HD);
    transpose_cast<<<256, 256, 0, stream>>>(Whh + (size_t)HD * HD, WhhT1, HD, HD);
    transpose_cast<<<16, 256, 0, stream>>>(Wo, WoT, HD, F);
    xcast<<<(B * S * F) / (256 * 4), 256, 0, stream>>>(x, xbf);

    u32* ctr   = sync;
    u32* epoch = sync + 64;
    void* args[] = {
        (void*)&xbf, (void*)&WfoldT, (void*)&bf0, (void*)&WhhT0,
        (void*)&WihT1, (void*)&WhhT1, (void*)&bf1,
        (void*)&h0p0, (void*)&h0p1, (void*)&h1p0, (void*)&h1p1,
        (void*)&Hbuf, (void*)&ctr, (void*)&epoch
    };
    hipLaunchCooperativeKernel((void*)rnn_p, dim3(NBLK), dim3(512),
                               args, 65536, stream);

    outgemm<<<192, 256, 0, stream>>>(Hbuf, WoT, bo, out);
}

// Round 7
// 6172.576 us; speedup vs baseline: 2.0532x; 2.0532x over previous
//
#include <hip/hip_runtime.h>
#include <hip/hip_bf16.h>

#define B    256
#define S    192
#define F    64
#define HD   1024
#define PRED 48
#define TSTART (S - 1 - PRED)   // 143
#define NBLK 512
#define NSLOT 48                // history rotation period (>= PRED, bijective tail)

typedef __attribute__((ext_vector_type(8))) short short8;
typedef __attribute__((ext_vector_type(4))) float f32x4;
typedef unsigned long long u64;
typedef unsigned int u32;

static __device__ __forceinline__ short f2bf(float f) {
    __hip_bfloat16 h = __float2bfloat16(f);
    return *reinterpret_cast<short*>(&h);
}

// sc1 write-through store (device coherence point = MALL). Proven R4/R6.
// Consumers use PLAIN cached loads on never-recently-cached addresses
// (48-slot rotation) -> first touch misses to MALL, re-reads hit L1/L2.
static __device__ __forceinline__ void st_state(short* p, short v) {
    __hip_atomic_store(p, v, __ATOMIC_RELAXED, __HIP_MEMORY_SCOPE_AGENT);
}

static __device__ __forceinline__ f32x4 mfma16(short8 a, short8 b, f32x4 c) {
    return __builtin_amdgcn_mfma_f32_16x16x32_bf16(a, b, c, 0, 0, 0);
}

// ---------------------------------------------------------------------------
// prep kernels (unchanged, proven rounds 1-6)
// ---------------------------------------------------------------------------
__global__ void fold_kernel(const float* __restrict__ Wh,
                            const float* __restrict__ Wih0,
                            float* __restrict__ Wfold) {
    const int n  = (blockIdx.x & 3) * 256 + threadIdx.x;
    const int f0 = (blockIdx.x >> 2) * 4;
    float a0 = 0.f, a1 = 0.f, a2 = 0.f, a3 = 0.f;
#pragma unroll 8
    for (int k = 0; k < HD; ++k) {
        const float w = Wih0[(size_t)k * HD + n];
        a0 += Wh[(f0 + 0) * HD + k] * w;
        a1 += Wh[(f0 + 1) * HD + k] * w;
        a2 += Wh[(f0 + 2) * HD + k] * w;
        a3 += Wh[(f0 + 3) * HD + k] * w;
    }
    Wfold[(f0 + 0) * HD + n] = a0;
    Wfold[(f0 + 1) * HD + n] = a1;
    Wfold[(f0 + 2) * HD + n] = a2;
    Wfold[(f0 + 3) * HD + n] = a3;
}

__global__ void bias_kernel(const float* __restrict__ bh,
                            const float* __restrict__ Wih0,
                            const float* __restrict__ bih,
                            const float* __restrict__ bhh,
                            float* __restrict__ bf0,
                            float* __restrict__ bf1) {
    const int n = blockIdx.x * 256 + threadIdx.x;
    float a = 0.f;
#pragma unroll 8
    for (int k = 0; k < HD; ++k) a += bh[k] * Wih0[(size_t)k * HD + n];
    bf0[n] = a + bih[n] + bhh[n];
    bf1[n] = bih[HD + n] + bhh[HD + n];
}

__global__ void transpose_cast(const float* __restrict__ src,
                               short* __restrict__ dst, int K, int N) {
    __shared__ float tile[64][65];
    const int nk = K >> 6;
    const int bk = blockIdx.x % nk;
    const int bn = blockIdx.x / nk;
    const int i  = threadIdx.x;
    {
        const int c4 = (i & 15) * 4;
        for (int it = 0; it < 4; ++it) {
            const int k = (i >> 4) + it * 16;
            const float4 v = *reinterpret_cast<const float4*>(
                &src[(size_t)(bk * 64 + k) * N + bn * 64 + c4]);
            tile[k][c4 + 0] = v.x; tile[k][c4 + 1] = v.y;
            tile[k][c4 + 2] = v.z; tile[k][c4 + 3] = v.w;
        }
    }
    __syncthreads();
    {
        const int n  = i >> 2;
        const int kb = (i & 3) * 16;
        short* dp = &dst[(size_t)(bn * 64 + n) * K + bk * 64 + kb];
#pragma unroll
        for (int j = 0; j < 16; ++j) dp[j] = f2bf(tile[kb + j][n]);
    }
}

__global__ void xcast(const float* __restrict__ x, short* __restrict__ xb) {
    const size_t i = ((size_t)blockIdx.x * 256 + threadIdx.x) * 4;
    const float4 v = *reinterpret_cast<const float4*>(&x[i]);
    short4 o;
    o.x = f2bf(v.x); o.y = f2bf(v.y); o.z = f2bf(v.z); o.w = f2bf(v.w);
    *reinterpret_cast<short4*>(&xb[i]) = o;
}

// ---------------------------------------------------------------------------
// K=1024 MFMA gemm, plain cached loads both operands (R2-proven pattern).
// ap = state row base (+kg*8), bp = weight col base (+kg*8), both [.][1024].
// ---------------------------------------------------------------------------
static __device__ __forceinline__ f32x4 gemmNN(const short* __restrict__ ap,
                                               const short* __restrict__ bp,
                                               f32x4 acc) {
#pragma unroll 8
    for (int k0 = 0; k0 < HD; k0 += 32) {
        const short8 a = *reinterpret_cast<const short8*>(ap + k0);
        const short8 b = *reinterpret_cast<const short8*>(bp + k0);
        acc = mfma16(a, b, acc);
    }
    return acc;
}

// R4-proven global barrier: monotonic counter + epoch, relaxed agent atomics.
// __syncthreads drains vmcnt(0) (sc1 stores at MALL) before arrival.
static __device__ __forceinline__ void gridbar(u32* ctr, u32* epoch, u32 target) {
    __syncthreads();
    if (threadIdx.x == 0) {
        const u32 a = __hip_atomic_fetch_add(ctr, 1u, __ATOMIC_RELAXED,
                                             __HIP_MEMORY_SCOPE_AGENT);
        if (a == target * NBLK - 1u) {
            __hip_atomic_store(epoch, target, __ATOMIC_RELAXED,
                               __HIP_MEMORY_SCOPE_AGENT);
        } else {
            while (__hip_atomic_load(epoch, __ATOMIC_RELAXED,
                                     __HIP_MEMORY_SCOPE_AGENT) < target)
                __builtin_amdgcn_s_sleep(2);
        }
    }
    __syncthreads();
}

// ---------------------------------------------------------------------------
// Persistent skewed recurrence with rotating fresh-address history.
// 512 blocks x 256 thr (2/CU, cooperative). Phase k: layer0 -> h0(k) (k<191),
// layer1 -> h1(k-1) (k>=1). Tile 16 rows x 64 cols per block.
// bid mapping ties colg to bid&7 (default XCD round-robin) so each XCD keeps
// one weight-slice pair L2-hot — heuristic only, correctness placement-free.
// State: sc1 write-through to slot k%48; plain cached reads of slot (k-1)%48
// (address not L2-cached for 48 phases -> guaranteed-fresh MALL fetch).
// ---------------------------------------------------------------------------
__global__ __launch_bounds__(256, 2) void rnn_hist(
    const short* __restrict__ xbf,
    const short* __restrict__ WfoldT, const float* __restrict__ bf0,
    const short* __restrict__ WhhT0, const short* __restrict__ WihT1,
    const short* __restrict__ WhhT1, const float* __restrict__ bf1,
    short* h0h, short* h1h, u32* ctr, u32* epoch) {

    const int bid   = blockIdx.x;
    const int xcd   = bid & 7;
    const int mm    = bid >> 3;               // 0..63
    const int layer = mm & 1;
    const int colg  = (xcd << 1) | ((mm >> 1) & 1);   // 0..15
    const int rowg  = mm >> 2;                // 0..15
    const int w  = (threadIdx.x >> 6) & 3;
    const int l  = threadIdx.x & 63;
    const int lr = l & 15, kg = l >> 4;
    const int m0 = rowg * 16;
    const int n0 = colg * 64 + w * 16;
    const int arow = m0 + lr, bcol = n0 + lr;
    const int rb = m0 + kg * 4;

    const float bb = (layer ? bf1 : bf0)[bcol];
    const short* wfp   = WfoldT + (size_t)bcol * F + kg * 8;   // layer0 x-path
    const short* whh0p = WhhT0 + (size_t)bcol * HD + kg * 8;
    const short* wih1p = WihT1 + (size_t)bcol * HD + kg * 8;
    const short* whh1p = WhhT1 + (size_t)bcol * HD + kg * 8;
    const size_t arow_off = (size_t)arow * HD + kg * 8;

    for (int k = 0; k < S; ++k) {
        if (layer == 0) {
            if (k < S - 1) {
                f32x4 acc = {0.f, 0.f, 0.f, 0.f};
                const short* xp = xbf + ((size_t)arow * S + k) * F + kg * 8;
                const short8 xa0 = *reinterpret_cast<const short8*>(xp);
                const short8 xa1 = *reinterpret_cast<const short8*>(xp + 32);
                acc = mfma16(xa0, *reinterpret_cast<const short8*>(wfp), acc);
                acc = mfma16(xa1, *reinterpret_cast<const short8*>(wfp + 32), acc);
                if (k > 0)
                    acc = gemmNN(h0h + (size_t)((k - 1) % NSLOT) * B * HD + arow_off,
                                 whh0p, acc);
                short* hd = h0h + (size_t)(k % NSLOT) * B * HD;
#pragma unroll
                for (int r = 0; r < 4; ++r)
                    st_state(&hd[(size_t)(rb + r) * HD + bcol],
                             f2bf(tanhf(acc[r] + bb)));
            }
        } else {
            if (k >= 1) {
                const int t = k - 1;
                f32x4 acc = {0.f, 0.f, 0.f, 0.f};
                acc = gemmNN(h0h + (size_t)((k - 1) % NSLOT) * B * HD + arow_off,
                             wih1p, acc);
                if (t > 0)
                    acc = gemmNN(h1h + (size_t)((t - 1) % NSLOT) * B * HD + arow_off,
                                 whh1p, acc);
                short* hd = h1h + (size_t)(t % NSLOT) * B * HD;
#pragma unroll
                for (int r = 0; r < 4; ++r)
                    st_state(&hd[(size_t)(rb + r) * HD + bcol],
                             f2bf(tanhf(acc[r] + bb)));
            }
        }
        if (k < S - 1) gridbar(ctr, epoch, (u32)(k + 1));
    }
}

// ---------------------------------------------------------------------------
// outgemm: out[b][p][f] = relu(h1(143+p)[b]) @ WoT + bo. Reads the history
// slots directly (t=143..190 -> slots (47+p)%48, bijective). relu applied on
// the bf16 A-fragment (sign test). Kernel boundary gives coherence.
// ---------------------------------------------------------------------------
__global__ __launch_bounds__(256) void outgemm(
    const short* __restrict__ h1h, const short* __restrict__ WoT,
    const float* __restrict__ bo, float* __restrict__ out) {
    const int w = threadIdx.x >> 6, l = threadIdx.x & 63;
    const int lr = l & 15, kg = l >> 4;
    const int m0 = blockIdx.x * 64 + w * 16;
    const int arow = m0 + lr;                 // 0..12287 = b*48+p
    const u32 bidx = (u32)arow / 48u;
    const u32 p    = (u32)arow % 48u;
    const u32 slot = (47u + p) % 48u;         // (143+p) % 48

    f32x4 acc[4] = {{0.f,0.f,0.f,0.f},{0.f,0.f,0.f,0.f},
                    {0.f,0.f,0.f,0.f},{0.f,0.f,0.f,0.f}};
    const short* ap = h1h + ((size_t)slot * B + bidx) * HD + kg * 8;
    const short* bp = WoT + (size_t)lr * HD + kg * 8;
#pragma unroll 4
    for (int k0 = 0; k0 < HD; k0 += 32) {
        short8 a = *reinterpret_cast<const short8*>(ap + k0);
#pragma unroll
        for (int j = 0; j < 8; ++j) a[j] = (a[j] < 0) ? (short)0 : a[j];  // relu
#pragma unroll
        for (int c = 0; c < 4; ++c) {
            const short8 b = *reinterpret_cast<const short8*>(bp + (size_t)c * 16 * HD + k0);
            acc[c] = mfma16(a, b, acc[c]);
        }
    }
    const int rb = m0 + kg * 4;
#pragma unroll
    for (int c = 0; c < 4; ++c) {
        const float bbv = bo[c * 16 + lr];
#pragma unroll
        for (int r = 0; r < 4; ++r)
            out[(size_t)(rb + r) * F + c * 16 + lr] = acc[c][r] + bbv;
    }
}

// ---------------------------------------------------------------------------
extern "C" void kernel_launch(void* const* d_in, const int* in_sizes, int n_in,
                              void* d_out, int out_size, void* d_ws, size_t ws_size,
                              hipStream_t stream) {
    const float* x   = (const float*)d_in[0];
    const float* Wh  = (const float*)d_in[1];
    const float* bh  = (const float*)d_in[2];
    const float* Wih = (const float*)d_in[3];
    const float* Whh = (const float*)d_in[4];
    const float* bih = (const float*)d_in[5];
    const float* bhh = (const float*)d_in[6];
    const float* Wo  = (const float*)d_in[7];
    const float* bo  = (const float*)d_in[8];
    float* out = (float*)d_out;

    char* p = (char*)d_ws;
    float* Wfold  = (float*)p; p += (size_t)F * HD * 4;              // 256 KB
    float* bf0    = (float*)p; p += HD * 4;
    float* bf1    = (float*)p; p += HD * 4;
    short* WfoldT = (short*)p; p += (size_t)HD * F * 2;              // 128 KB
    short* WhhT0  = (short*)p; p += (size_t)HD * HD * 2;             // 2 MB
    short* WihT1  = (short*)p; p += (size_t)HD * HD * 2;
    short* WhhT1  = (short*)p; p += (size_t)HD * HD * 2;
    short* WoT    = (short*)p; p += (size_t)F * HD * 2;              // 128 KB
    short* h0h    = (short*)p; p += (size_t)NSLOT * B * HD * 2;      // 24 MB
    short* h1h    = (short*)p; p += (size_t)NSLOT * B * HD * 2;      // 24 MB
    short* xbf    = (short*)p; p += (size_t)B * S * F * 2;           // 6.3 MB
    u32*   sync   = (u32*)p;  p += 4096;

    hipMemsetAsync(sync, 0, 4096, stream);

    fold_kernel<<<64, 256, 0, stream>>>(Wh, Wih, Wfold);
    bias_kernel<<<4, 256, 0, stream>>>(bh, Wih, bih, bhh, bf0, bf1);
    transpose_cast<<<16, 256, 0, stream>>>(Wfold, WfoldT, F, HD);
    transpose_cast<<<256, 256, 0, stream>>>(Whh, WhhT0, HD, HD);
    transpose_cast<<<256, 256, 0, stream>>>(Wih + (size_t)HD * HD, WihT1, HD, HD);
    transpose_cast<<<256, 256, 0, stream>>>(Whh + (size_t)HD * HD, WhhT1, HD, HD);
    transpose_cast<<<16, 256, 0, stream>>>(Wo, WoT, HD, F);
    xcast<<<(B * S * F) / (256 * 4), 256, 0, stream>>>(x, xbf);

    u32* ctr   = sync;
    u32* epoch = sync + 64;
    void* args[] = {
        (void*)&xbf, (void*)&WfoldT, (void*)&bf0, (void*)&WhhT0,
        (void*)&WihT1, (void*)&WhhT1, (void*)&bf1,
        (void*)&h0h, (void*)&h1h, (void*)&ctr, (void*)&epoch
    };
    hipLaunchCooperativeKernel((void*)rnn_hist, dim3(NBLK), dim3(256),
                               args, 0, stream);

    outgemm<<<192, 256, 0, stream>>>(h1h, WoT, bo, out);
}

// Round 8
// 3804.531 us; speedup vs baseline: 3.3312x; 1.6224x over previous
//
#include <hip/hip_runtime.h>
#include <hip/hip_bf16.h>

#define B    256
#define S    192
#define F    64
#define HD   1024
#define PRED 48
#define TSTART (S - 1 - PRED)   // 143

typedef __attribute__((ext_vector_type(8))) short short8;
typedef __attribute__((ext_vector_type(4))) float f32x4;
typedef unsigned int u32;

static __device__ __forceinline__ short f2bf(float f) {
    __hip_bfloat16 h = __float2bfloat16(f);
    return *reinterpret_cast<short*>(&h);
}
static __device__ __forceinline__ f32x4 mfma16(short8 a, short8 b, f32x4 c) {
    return __builtin_amdgcn_mfma_f32_16x16x32_bf16(a, b, c, 0, 0, 0);
}
static __device__ __forceinline__ short8 ld8(const short* p) {
    return *reinterpret_cast<const short8*>(p);
}

// ---------------------------------------------------------------------------
// prep kernels (proven rounds 1-7)
// ---------------------------------------------------------------------------
__global__ void fold_kernel(const float* __restrict__ Wh,
                            const float* __restrict__ Wih0,
                            float* __restrict__ Wfold) {
    const int n  = (blockIdx.x & 3) * 256 + threadIdx.x;
    const int f0 = (blockIdx.x >> 2) * 4;
    float a0 = 0.f, a1 = 0.f, a2 = 0.f, a3 = 0.f;
#pragma unroll 8
    for (int k = 0; k < HD; ++k) {
        const float w = Wih0[(size_t)k * HD + n];
        a0 += Wh[(f0 + 0) * HD + k] * w;
        a1 += Wh[(f0 + 1) * HD + k] * w;
        a2 += Wh[(f0 + 2) * HD + k] * w;
        a3 += Wh[(f0 + 3) * HD + k] * w;
    }
    Wfold[(f0 + 0) * HD + n] = a0;
    Wfold[(f0 + 1) * HD + n] = a1;
    Wfold[(f0 + 2) * HD + n] = a2;
    Wfold[(f0 + 3) * HD + n] = a3;
}

__global__ void bias_kernel(const float* __restrict__ bh,
                            const float* __restrict__ Wih0,
                            const float* __restrict__ bih,
                            const float* __restrict__ bhh,
                            float* __restrict__ bf0,
                            float* __restrict__ bf1) {
    const int n = blockIdx.x * 256 + threadIdx.x;
    float a = 0.f;
#pragma unroll 8
    for (int k = 0; k < HD; ++k) a += bh[k] * Wih0[(size_t)k * HD + n];
    bf0[n] = a + bih[n] + bhh[n];
    bf1[n] = bih[HD + n] + bhh[HD + n];
}

__global__ void transpose_cast(const float* __restrict__ src,
                               short* __restrict__ dst, int K, int N) {
    __shared__ float tile[64][65];
    const int nk = K >> 6;
    const int bk = blockIdx.x % nk;
    const int bn = blockIdx.x / nk;
    const int i  = threadIdx.x;
    {
        const int c4 = (i & 15) * 4;
        for (int it = 0; it < 4; ++it) {
            const int k = (i >> 4) + it * 16;
            const float4 v = *reinterpret_cast<const float4*>(
                &src[(size_t)(bk * 64 + k) * N + bn * 64 + c4]);
            tile[k][c4 + 0] = v.x; tile[k][c4 + 1] = v.y;
            tile[k][c4 + 2] = v.z; tile[k][c4 + 3] = v.w;
        }
    }
    __syncthreads();
    {
        const int n  = i >> 2;
        const int kb = (i & 3) * 16;
        short* dp = &dst[(size_t)(bn * 64 + n) * K + bk * 64 + kb];
#pragma unroll
        for (int j = 0; j < 16; ++j) dp[j] = f2bf(tile[kb + j][n]);
    }
}

__global__ void xcast(const float* __restrict__ x, short* __restrict__ xb) {
    const size_t i = ((size_t)blockIdx.x * 256 + threadIdx.x) * 4;
    const float4 v = *reinterpret_cast<const float4*>(&x[i]);
    short4 o;
    o.x = f2bf(v.x); o.y = f2bf(v.y); o.z = f2bf(v.z); o.w = f2bf(v.w);
    *reinterpret_cast<short4*>(&xb[i]) = o;
}

// ---------------------------------------------------------------------------
// stageA: copy 32 rows x 1024 bf16 of state (rows row0..row0+31) into 64KB
// LDS, XOR-swizzled (16B slot ^= (row&7)<<4) so stride-2048B ds_read_b128
// across 16 rows spreads over 8 banks-groups (2-way = free, m136).
// 512 thr x 8 iters x 16B. Plain cached loads (kernel-boundary coherence).
// ---------------------------------------------------------------------------
static __device__ __forceinline__ void stageA(char* lds, const short* __restrict__ src,
                                              int row0) {
    const int tid = threadIdx.x;
#pragma unroll
    for (int it = 0; it < 8; ++it) {
        const int c = it * 512 + tid;            // 16B chunk id, 4096 total
        const int r = c >> 7;                    // 0..31
        const int o = (c & 127) << 4;            // byte offset in row
        const f32x4 v = *reinterpret_cast<const f32x4*>(
            (const char*)(src + (size_t)(row0 + r) * HD) + o);
        *reinterpret_cast<f32x4*>(lds + r * 2048 + (o ^ ((r & 7) << 4))) = v;
    }
}

// ---------------------------------------------------------------------------
// gemmLG: 16x16 output frag, K=1024; A from swizzled LDS (16 rows at rl),
// B from global (L2-hot weight col-slice). 2-way K-split for MFMA ILP.
// ---------------------------------------------------------------------------
static __device__ __forceinline__ f32x4 gemmLG(const char* ldsA, int rlbase,
                                               int kgoff, int aswz,
                                               const short* __restrict__ bp) {
    f32x4 acc0 = {0.f, 0.f, 0.f, 0.f}, acc1 = {0.f, 0.f, 0.f, 0.f};
#pragma unroll 8
    for (int k0 = 0; k0 < 512; k0 += 32) {
        const short8 aA = *reinterpret_cast<const short8*>(
            ldsA + rlbase + ((kgoff + 2 * k0) ^ aswz));
        acc0 = mfma16(aA, ld8(bp + k0), acc0);
        const short8 aB = *reinterpret_cast<const short8*>(
            ldsA + rlbase + ((kgoff + 2 * (k0 + 512)) ^ aswz));
        acc1 = mfma16(aB, ld8(bp + k0 + 512), acc1);
    }
    return acc0 + acc1;
}

// ---------------------------------------------------------------------------
// step_fused: one skewed phase k. 256 blocks x 512 thr, 64KB dynamic LDS.
// bid<128: layer0 -> h0(k) = tanh(x(k)@Wfold + h0(k-1)@Whh0 + bf0) [k<191]
// bid>=128: layer1 -> h1(k-1) = tanh(h0(k-1)@Wih1 + h1(k-2)@Whh1 + bf1) [k>=1]
// Block tile: 32 rows x 64 cols; wave = 16x16 frag (mh x nq).
// All loads/stores plain cached — coherence from kernel boundaries (R2-proven).
// ---------------------------------------------------------------------------
__global__ __launch_bounds__(512) void step_fused(
    int k, const short* __restrict__ xbf,
    const short* __restrict__ WfoldT, const float* __restrict__ bf0,
    const short* __restrict__ WhhT0, const short* __restrict__ WihT1,
    const short* __restrict__ WhhT1, const float* __restrict__ bf1,
    const short* __restrict__ h0prev, short* __restrict__ h0cur,
    const short* __restrict__ h1prev, short* __restrict__ h1cur,
    short* __restrict__ Hbuf) {

    extern __shared__ char lds[];                // 64 KB

    const int bid   = blockIdx.x;
    const int layer = bid >> 7;
    const int lb    = bid & 127;
    const int rt    = lb >> 4;                   // 0..7  (32-row group)
    const int ct    = lb & 15;                   // 0..15 (64-col group)
    const int w     = threadIdx.x >> 6;          // 0..7
    const int mh    = w & 1;                     // 16-row half
    const int nq    = w >> 1;                    // 0..3 (16-col quarter)
    const int l     = threadIdx.x & 63;
    const int lr    = l & 15, kg = l >> 4;
    const int row0  = rt * 32;
    const int m0    = row0 + mh * 16;
    const int n0    = ct * 64 + nq * 16;
    const int col   = n0 + lr;
    const int rb    = m0 + kg * 4;
    const int rl    = mh * 16 + lr;              // local A row
    const int rlbase = rl * 2048;
    const int kgoff  = kg * 16;
    const int aswz   = (rl & 7) << 4;

    if (layer == 0) {
        if (k >= S - 1) return;
        f32x4 acc = {0.f, 0.f, 0.f, 0.f};
        // x-path: K=64
        const short* xp = xbf + ((size_t)(m0 + lr) * S + k) * F + kg * 8;
        const short* wf = WfoldT + (size_t)col * F + kg * 8;
        acc = mfma16(ld8(xp),      ld8(wf),      acc);
        acc = mfma16(ld8(xp + 32), ld8(wf + 32), acc);
        if (k > 0) {
            stageA(lds, h0prev, row0);
            __syncthreads();
            acc += gemmLG(lds, rlbase, kgoff, aswz,
                          WhhT0 + (size_t)col * HD + kg * 8);
        }
        const float bb = bf0[col];
#pragma unroll
        for (int r = 0; r < 4; ++r)
            h0cur[(size_t)(rb + r) * HD + col] = f2bf(tanhf(acc[r] + bb));
    } else {
        if (k < 1) return;
        const int t = k - 1;
        stageA(lds, h0prev, row0);               // h0(k-1), written last launch
        __syncthreads();
        f32x4 acc = gemmLG(lds, rlbase, kgoff, aswz,
                           WihT1 + (size_t)col * HD + kg * 8);
        if (t > 0) {
            __syncthreads();                     // gemm1 LDS reads done
            stageA(lds, h1prev, row0);           // h1(t-1)
            __syncthreads();
            acc += gemmLG(lds, rlbase, kgoff, aswz,
                          WhhT1 + (size_t)col * HD + kg * 8);
        }
        const float bb = bf1[col];
#pragma unroll
        for (int r = 0; r < 4; ++r) {
            const float v = tanhf(acc[r] + bb);
            h1cur[(size_t)(rb + r) * HD + col] = f2bf(v);
            if (t >= TSTART) {
                const float rv = v > 0.f ? v : 0.f;
                Hbuf[((size_t)(rb + r) * PRED + (t - TSTART)) * HD + col] = f2bf(rv);
            }
        }
    }
}

// ---------------------------------------------------------------------------
// outgemm: out = H(relu'd) @ WoT + bo ; M=12288, N=64, K=1024. (R2-proven)
// ---------------------------------------------------------------------------
__global__ __launch_bounds__(256) void outgemm(
    const short* __restrict__ Hbuf, const short* __restrict__ WoT,
    const float* __restrict__ bo, float* __restrict__ out) {
    const int w = threadIdx.x >> 6, l = threadIdx.x & 63;
    const int lr = l & 15, kg = l >> 4;
    const int m0 = blockIdx.x * 64 + w * 16;
    const int arow = m0 + lr;

    f32x4 acc[4] = {{0.f,0.f,0.f,0.f},{0.f,0.f,0.f,0.f},
                    {0.f,0.f,0.f,0.f},{0.f,0.f,0.f,0.f}};
    const short* ap = Hbuf + (size_t)arow * HD + kg * 8;
    const short* bp = WoT + (size_t)lr * HD + kg * 8;
#pragma unroll 4
    for (int k0 = 0; k0 < HD; k0 += 32) {
        const short8 a = ld8(ap + k0);
#pragma unroll
        for (int c = 0; c < 4; ++c)
            acc[c] = mfma16(a, ld8(bp + (size_t)c * 16 * HD + k0), acc[c]);
    }
    const int rb = m0 + kg * 4;
#pragma unroll
    for (int c = 0; c < 4; ++c) {
        const float bbv = bo[c * 16 + lr];
#pragma unroll
        for (int r = 0; r < 4; ++r)
            out[(size_t)(rb + r) * F + c * 16 + lr] = acc[c][r] + bbv;
    }
}

// ---------------------------------------------------------------------------
extern "C" void kernel_launch(void* const* d_in, const int* in_sizes, int n_in,
                              void* d_out, int out_size, void* d_ws, size_t ws_size,
                              hipStream_t stream) {
    const float* x   = (const float*)d_in[0];
    const float* Wh  = (const float*)d_in[1];
    const float* bh  = (const float*)d_in[2];
    const float* Wih = (const float*)d_in[3];
    const float* Whh = (const float*)d_in[4];
    const float* bih = (const float*)d_in[5];
    const float* bhh = (const float*)d_in[6];
    const float* Wo  = (const float*)d_in[7];
    const float* bo  = (const float*)d_in[8];
    float* out = (float*)d_out;

    char* p = (char*)d_ws;
    float* Wfold  = (float*)p; p += (size_t)F * HD * 4;
    float* bf0    = (float*)p; p += HD * 4;
    float* bf1    = (float*)p; p += HD * 4;
    short* WfoldT = (short*)p; p += (size_t)HD * F * 2;
    short* WhhT0  = (short*)p; p += (size_t)HD * HD * 2;
    short* WihT1  = (short*)p; p += (size_t)HD * HD * 2;
    short* WhhT1  = (short*)p; p += (size_t)HD * HD * 2;
    short* WoT    = (short*)p; p += (size_t)F * HD * 2;
    short* h0b0   = (short*)p; p += (size_t)B * HD * 2;
    short* h0b1   = (short*)p; p += (size_t)B * HD * 2;
    short* h1b0   = (short*)p; p += (size_t)B * HD * 2;
    short* h1b1   = (short*)p; p += (size_t)B * HD * 2;
    short* Hbuf   = (short*)p; p += (size_t)B * PRED * HD * 2;
    short* xbf    = (short*)p; p += (size_t)B * S * F * 2;

    fold_kernel<<<64, 256, 0, stream>>>(Wh, Wih, Wfold);
    bias_kernel<<<4, 256, 0, stream>>>(bh, Wih, bih, bhh, bf0, bf1);
    transpose_cast<<<16, 256, 0, stream>>>(Wfold, WfoldT, F, HD);
    transpose_cast<<<256, 256, 0, stream>>>(Whh, WhhT0, HD, HD);
    transpose_cast<<<256, 256, 0, stream>>>(Wih + (size_t)HD * HD, WihT1, HD, HD);
    transpose_cast<<<256, 256, 0, stream>>>(Whh + (size_t)HD * HD, WhhT1, HD, HD);
    transpose_cast<<<16, 256, 0, stream>>>(Wo, WoT, HD, F);
    xcast<<<(B * S * F) / (256 * 4), 256, 0, stream>>>(x, xbf);

    short* h0b[2] = {h0b0, h0b1};
    short* h1b[2] = {h1b0, h1b1};
    for (int k = 0; k < S; ++k) {
        // h0prev=h0(k-1), h0cur=h0(k); h1prev=h1(k-2), h1cur=h1(k-1)
        step_fused<<<256, 512, 65536, stream>>>(
            k, xbf, WfoldT, bf0, WhhT0, WihT1, WhhT1, bf1,
            h0b[(k + 1) & 1], h0b[k & 1],
            h1b[k & 1],       h1b[(k + 1) & 1],
            Hbuf);
    }
    outgemm<<<192, 256, 0, stream>>>(Hbuf, WoT, bo, out);
}